// Round 3
// baseline (326.644 us; speedup 1.0000x reference)
//
#include <hip/hip_runtime.h>

// QPChargeNormalization: per batch row b (n = 8192 = 4096 iso + 4096 aniso):
//   h = u/2 = (sum(charge[b]) - q.c) / (q.q);  x = c + h*q
// One 256-thread block per row. Payload (16 vec4 c + 16 vec4 q per thread)
// is PINNED in VGPRs via empty-asm so the compiler cannot rematerialize the
// epilogue with global reloads (R1: VGPR=44 proved it was reloading -> second
// full latency chain per block -> only 2.4 TB/s). Single barrier; every
// thread computes h redundantly. Nontemporal vec4 stores (output never
// re-read; keep LLC for inputs). Native ext_vector_type instead of HIP
// float4 because __builtin_nontemporal_store rejects HIP_vector_type.

#define HALF_N 4096   // elements per row in each of the iso/aniso halves
#define BLOCK  256

typedef float v4f __attribute__((ext_vector_type(4)));

// Pin a float in a VGPR: compiler must treat it as modified -> cannot reload
// from memory in the epilogue.
#define KEEP(x) asm volatile("" : "+v"(x))
#define KEEP4(v) do { KEEP((v).x); KEEP((v).y); KEEP((v).z); KEEP((v).w); } while (0)

__global__ __launch_bounds__(BLOCK, 2) void qp_charge_norm_kernel(
    const float* __restrict__ c_iso,
    const float* __restrict__ c_aniso,
    const float* __restrict__ q_iso,
    const float* __restrict__ q_aniso,
    const float* __restrict__ charge,   // [B, 256]
    float* __restrict__ out,            // [B*4096 iso][B*4096 aniso]
    int B)
{
    const int b   = blockIdx.x;
    const int tid = threadIdx.x;

    const v4f* ci = (const v4f*)(c_iso   + (size_t)b * HALF_N);
    const v4f* ca = (const v4f*)(c_aniso + (size_t)b * HALF_N);
    const v4f* qi = (const v4f*)(q_iso   + (size_t)b * HALF_N);
    const v4f* qa = (const v4f*)(q_aniso + (size_t)b * HALF_N);

    // ---- Phase 1: load everything (coalesced vec4, j*256+tid) & pin ----
    v4f cv[8], qv[8];
#pragma unroll
    for (int j = 0; j < 4; ++j) {
        cv[j]     = ci[j * BLOCK + tid];
        qv[j]     = qi[j * BLOCK + tid];
        cv[j + 4] = ca[j * BLOCK + tid];
        qv[j + 4] = qa[j * BLOCK + tid];
    }
    float Qp = charge[(size_t)b * 256 + tid];
#pragma unroll
    for (int j = 0; j < 8; ++j) { KEEP4(cv[j]); KEEP4(qv[j]); }

    float qc = 0.0f, qq = 0.0f;
#pragma unroll
    for (int j = 0; j < 8; ++j) {
        qc += qv[j].x * cv[j].x + qv[j].y * cv[j].y
            + qv[j].z * cv[j].z + qv[j].w * cv[j].w;
        qq += qv[j].x * qv[j].x + qv[j].y * qv[j].y
            + qv[j].z * qv[j].z + qv[j].w * qv[j].w;
    }

    // ---- Phase 2: wave reduce -> LDS partials -> every thread computes h ----
#pragma unroll
    for (int off = 32; off > 0; off >>= 1) {
        qc += __shfl_down(qc, off, 64);
        qq += __shfl_down(qq, off, 64);
        Qp += __shfl_down(Qp, off, 64);
    }

    __shared__ float s_qc[4], s_qq[4], s_Q[4];
    const int wave = tid >> 6;
    if ((tid & 63) == 0) { s_qc[wave] = qc; s_qq[wave] = qq; s_Q[wave] = Qp; }
    __syncthreads();
    const float tqc = s_qc[0] + s_qc[1] + s_qc[2] + s_qc[3];
    const float tqq = s_qq[0] + s_qq[1] + s_qq[2] + s_qq[3];
    const float tQ  = s_Q[0]  + s_Q[1]  + s_Q[2]  + s_Q[3];
    const float h   = (tQ - tqc) / tqq;   // u/2, computed redundantly per thread

    // ---- Phase 3: epilogue, pure FMA + nontemporal vec4 store (no reloads) ----
    v4f* oi = (v4f*)(out + (size_t)b * HALF_N);
    v4f* oa = (v4f*)(out + (size_t)B * HALF_N + (size_t)b * HALF_N);
#pragma unroll
    for (int j = 0; j < 4; ++j) {
        v4f r = cv[j] + h * qv[j];
        __builtin_nontemporal_store(r, &oi[j * BLOCK + tid]);
        v4f s = cv[j + 4] + h * qv[j + 4];
        __builtin_nontemporal_store(s, &oa[j * BLOCK + tid]);
    }
}

extern "C" void kernel_launch(void* const* d_in, const int* in_sizes, int n_in,
                              void* d_out, int out_size, void* d_ws, size_t ws_size,
                              hipStream_t stream) {
    const float* c_iso   = (const float*)d_in[0];
    const float* c_aniso = (const float*)d_in[1];
    const float* q_iso   = (const float*)d_in[2];
    const float* q_aniso = (const float*)d_in[3];
    const float* charge  = (const float*)d_in[4];
    float* out = (float*)d_out;

    const int B = in_sizes[0] / HALF_N;   // 4096

    qp_charge_norm_kernel<<<B, BLOCK, 0, stream>>>(
        c_iso, c_aniso, q_iso, q_aniso, charge, out, B);
}